// Round 7
// baseline (111.551 us; speedup 1.0000x reference)
//
#include <hip/hip_runtime.h>
#include <stdint.h>

typedef float  f32x4  __attribute__((ext_vector_type(4)));
typedef short  bf16x8 __attribute__((ext_vector_type(8)));
typedef int    i32x4  __attribute__((ext_vector_type(4)));
typedef unsigned int u32x2 __attribute__((ext_vector_type(2)));

#define C1f 0.70710678118654752f
#define C2f 0.5f
#define C3f 0.35355339059327373f

#define MT 64           // M-tile rows per block
#define RB 1040         // LDS row stride bytes (512*2 + 16 pad)
#define NT 512          // 8 waves

__device__ __forceinline__ unsigned int f2b(float f) {
    unsigned int u; __builtin_memcpy(&u, &f, 4);
    u += 0x7fffu + ((u >> 16) & 1u);          // RTNE f32 -> bf16
    return u >> 16;
}
__device__ __forceinline__ unsigned int pack2(float lo, float hi) {
    return f2b(lo) | (f2b(hi) << 16);
}
__device__ __forceinline__ bf16x8 cast8(i32x4 v) {
    bf16x8 r; __builtin_memcpy(&r, &v, 16); return r;
}

// G[o][i0..i0+7] as bf16x8.  G = composed DWT -> blockdiag(W) -> IDWT matrix:
// G[o][i] = 1/8*Wa[o/8][i/8] + 1/8*s2(o)s2(i)*W2[o/8][i/8]
//         + 1/4*s1(o)s1(i)*W1[o/4][i/4] + 1/2*s0(o)s0(i)*W0[o/2][i/2]
__device__ __forceinline__ bf16x8 g_frag(int o, int i0,
        const float* __restrict__ W0, const float* __restrict__ W1,
        const float* __restrict__ W2, const float* __restrict__ Wa)
{
    const float s0o = (o & 1) ? -1.f : 1.f;
    const float s1o = ((o >> 1) & 1) ? -1.f : 1.f;
    const float s2o = ((o >> 2) & 1) ? -1.f : 1.f;
    const float4 w0 = *(const float4*)(W0 + (o >> 1) * 256 + (i0 >> 1));
    const float2 w1 = *(const float2*)(W1 + (o >> 2) * 128 + (i0 >> 2));
    const float  w2 = W2[(o >> 3) * 64 + (i0 >> 3)];
    const float  wa = Wa[(o >> 3) * 64 + (i0 >> 3)];
    const float base = 0.125f * wa;
    const float c2   = 0.125f * s2o * w2;
    const float c1   = 0.25f  * s1o;
    const float c0   = 0.5f   * s0o;
    const float w0a[4] = { w0.x, w0.y, w0.z, w0.w };
    const float w1a[2] = { w1.x, w1.y };
    float g[8];
    #pragma unroll
    for (int e = 0; e < 8; ++e) {
        const float t2 = ((e >> 2) & 1) ? -c2 : c2;
        const float t1 = (((e >> 1) & 1) ? -c1 : c1) * w1a[e >> 2];
        const float t0 = ((e & 1) ? -c0 : c0) * w0a[e >> 1];
        g[e] = base + t2 + t1 + t0;
    }
    i32x4 p = { (int)pack2(g[0],g[1]), (int)pack2(g[2],g[3]),
                (int)pack2(g[4],g[5]), (int)pack2(g[6],g[7]) };
    return cast8(p);
}

// prep: build G in MFMA-fragment blob order + bias vector g.
// blob = otg*16 + ks (512 blobs); lane holds G[o=otg*16+(lane&15)][k=ks*32+(lane>>4)*8+e].
// 16B/lane, 1KB/blob, 512KB total; bias g (512 f32) after.
__global__ void prep(const float* __restrict__ W0, const float* __restrict__ b0,
                     const float* __restrict__ W1, const float* __restrict__ b1,
                     const float* __restrict__ W2, const float* __restrict__ b2,
                     const float* __restrict__ Wa, const float* __restrict__ ba,
                     unsigned short* __restrict__ ws)
{
    const int gid  = blockIdx.x * 256 + threadIdx.x;   // 32768 threads
    const int blob = gid >> 6, lane = gid & 63;
    const int otg  = blob >> 4, ks = blob & 15;
    const int o  = otg * 16 + (lane & 15);
    const int i0 = ks * 32 + ((lane >> 4) * 8);
    bf16x8 f = g_frag(o, i0, W0, W1, W2, Wa);
    i32x4 p; __builtin_memcpy(&p, &f, 16);
    *(i32x4*)(ws + blob * 512 + lane * 8) = p;
    if (gid < 512) {
        float* gv = (float*)(ws + 262144);
        const int oo = gid;
        const float s0 = (oo & 1) ? -C1f : C1f;
        const float s1 = ((oo >> 1) & 1) ? -C2f : C2f;
        const float s2 = ((oo >> 2) & 1) ? -C3f : C3f;
        gv[oo] = C3f * ba[oo >> 3] + s2 * b2[oo >> 3] + s1 * b1[oo >> 2] + s0 * b0[oo >> 1];
    }
}

// main: out[65536x512] = x @ G^T + g.
// Block: 64 rows x 512 cols, 8 waves; wave owns 64 out-cols (4 n-tiles), all 4 m-tiles.
// mfma(G_frag, x_frag, acc): C col(lane&15)=x-row, row((lane>>4)*4+j)=out-col
// -> lane holds 4 consecutive out cols => float4 stores.
template<int USE_WS>
__global__ __launch_bounds__(NT, 4)
void wavelet_gemm(const float* __restrict__ x,
                  const float* __restrict__ W0, const float* __restrict__ b0,
                  const float* __restrict__ W1, const float* __restrict__ b1,
                  const float* __restrict__ W2, const float* __restrict__ b2,
                  const float* __restrict__ Wa, const float* __restrict__ ba,
                  const unsigned short* __restrict__ wsb,
                  float* __restrict__ out)
{
    __shared__ char lds[MT * RB];

    const int tid  = threadIdx.x;
    const int lane = tid & 63;
    const int wave = tid >> 6;
    const long rowblk = (long)blockIdx.x * MT;

    // ---- stage x tile (64x512 f32 = 8192 float4) -> bf16 LDS, fully coalesced ----
    const f32x4* xb = (const f32x4*)(x + rowblk * 512);
    {
        f32x4 v[16];
        #pragma unroll
        for (int k = 0; k < 16; ++k) v[k] = xb[k * NT + tid];
        #pragma unroll
        for (int k = 0; k < 16; ++k) {
            const int f = k * NT + tid;       // float4 index in [0, 8192)
            const int row = f >> 7, c4 = f & 127;
            u32x2 p = { pack2(v[k].x, v[k].y), pack2(v[k].z, v[k].w) };
            *(u32x2*)(lds + row * RB + c4 * 8) = p;
        }
    }

    // bias for this wave's 64 cols (4 n-tiles; lane holds 4 consecutive cols)
    f32x4 gv4[4];
    #pragma unroll
    for (int n = 0; n < 4; ++n) {
        const int col0 = wave * 64 + n * 16 + ((lane >> 4) << 2);
        if (USE_WS) {
            const float4 g4 = *(const float4*)((const float*)(wsb + 262144) + col0);
            gv4[n] = f32x4{ g4.x, g4.y, g4.z, g4.w };
        } else {
            #pragma unroll
            for (int j = 0; j < 4; ++j) {
                const int col = col0 + j;
                const float s0 = (col & 1) ? -C1f : C1f;
                const float s1 = ((col >> 1) & 1) ? -C2f : C2f;
                const float s2 = ((col >> 2) & 1) ? -C3f : C3f;
                gv4[n][j] = C3f * ba[col >> 3] + s2 * b2[col >> 3] + s1 * b1[col >> 2] + s0 * b0[col >> 1];
            }
        }
    }
    __syncthreads();

    // x fragment: lane holds x[m*16+(lane&15)][ks*32+(lane>>4)*8+e]
    auto ldA = [&](int m, int ks) -> bf16x8 {
        const char* p = lds + (m * 16 + (lane & 15)) * RB + ks * 64 + ((lane >> 4) * 16);
        return cast8(*(const i32x4*)p);
    };
    // G fragment for n-tile otg at K-step ks
    auto ldB = [&](int n, int ks) -> bf16x8 {
        if (USE_WS) {
            return cast8(*(const i32x4*)(wsb + (((wave * 4 + n) * 16 + ks) * 512) + lane * 8));
        } else {
            return g_frag((wave * 4 + n) * 16 + (lane & 15),
                          ks * 32 + ((lane >> 4) * 8), W0, W1, W2, Wa);
        }
    };

    #pragma unroll 1
    for (int m = 0; m < 4; ++m) {
        f32x4 acc[4] = {};
        #pragma unroll 1
        for (int kh = 0; kh < 2; ++kh) {
            bf16x8 A[8];
            #pragma unroll
            for (int kk = 0; kk < 8; ++kk) A[kk] = ldA(m, kh * 8 + kk);
            #pragma unroll 1
            for (int n = 0; n < 4; ++n) {
                bf16x8 B[8];
                #pragma unroll
                for (int kk = 0; kk < 8; ++kk) B[kk] = ldB(n, kh * 8 + kk);
                #pragma unroll
                for (int kk = 0; kk < 8; ++kk)
                    acc[n] = __builtin_amdgcn_mfma_f32_16x16x32_bf16(B[kk], A[kk], acc[n], 0, 0, 0);
            }
        }
        // store this m-tile: 16 rows x 64 cols, float4 per lane per n
        const long rbase = (rowblk + m * 16 + (lane & 15)) * 512;
        #pragma unroll
        for (int n = 0; n < 4; ++n) {
            f32x4 vst = acc[n] + gv4[n];
            *(f32x4*)(out + rbase + wave * 64 + n * 16 + ((lane >> 4) << 2)) = vst;
        }
    }
}

extern "C" void kernel_launch(void* const* d_in, const int* in_sizes, int n_in,
                              void* d_out, int out_size, void* d_ws, size_t ws_size,
                              hipStream_t stream)
{
    const float* x  = (const float*)d_in[0];
    const float* W0 = (const float*)d_in[1];
    const float* b0 = (const float*)d_in[2];
    const float* W1 = (const float*)d_in[3];
    const float* b1 = (const float*)d_in[4];
    const float* W2 = (const float*)d_in[5];
    const float* b2 = (const float*)d_in[6];
    const float* Wa = (const float*)d_in[7];
    const float* ba = (const float*)d_in[8];
    float* out = (float*)d_out;

    const int nrows = in_sizes[0] / 512;      // 65536
    const int nblk  = nrows / MT;             // 1024

    if (ws_size >= (size_t)(524288 + 2048)) {
        unsigned short* ws = (unsigned short*)d_ws;
        prep<<<128, 256, 0, stream>>>(W0, b0, W1, b1, W2, b2, Wa, ba, ws);
        wavelet_gemm<1><<<nblk, NT, 0, stream>>>(x, W0, b0, W1, b1, W2, b2, Wa, ba, ws, out);
    } else {
        wavelet_gemm<0><<<nblk, NT, 0, stream>>>(x, W0, b0, W1, b1, W2, b2, Wa, ba, nullptr, out);
    }
}

// Round 8
// 75.689 us; speedup vs baseline: 1.4738x; 1.4738x over previous
//
#include <hip/hip_runtime.h>
#include <stdint.h>

typedef float  f32x4  __attribute__((ext_vector_type(4)));
typedef short  bf16x8 __attribute__((ext_vector_type(8)));
typedef int    i32x4  __attribute__((ext_vector_type(4)));
typedef unsigned int u32x2 __attribute__((ext_vector_type(2)));

#define C1f 0.70710678118654752f
#define C2f 0.5f
#define C3f 0.35355339059327373f

#define NT 1024         // 16 waves
#define CH 32           // chunk rows
#define RB 1040         // LDS row stride bytes (512*2 + 16 pad)
#define RPB 256         // rows per block
#define NCHUNK (RPB/CH) // 8

__device__ __forceinline__ unsigned int f2b(float f) {
    unsigned int u; __builtin_memcpy(&u, &f, 4);
    u += 0x7fffu + ((u >> 16) & 1u);          // RTNE f32 -> bf16
    return u >> 16;
}
__device__ __forceinline__ unsigned int pack2(float lo, float hi) {
    return f2b(lo) | (f2b(hi) << 16);
}
__device__ __forceinline__ bf16x8 cast8(i32x4 v) {
    bf16x8 r; __builtin_memcpy(&r, &v, 16); return r;
}

// G[o][i0..i0+7] as bf16x8.  G = composed DWT -> blockdiag(W) -> IDWT matrix:
// G[o][i] = 1/8*Wa[o/8][i/8] + 1/8*s2(o)s2(i)*W2[o/8][i/8]
//         + 1/4*s1(o)s1(i)*W1[o/4][i/4] + 1/2*s0(o)s0(i)*W0[o/2][i/2]
__device__ __forceinline__ bf16x8 g_frag(int o, int i0,
        const float* __restrict__ W0, const float* __restrict__ W1,
        const float* __restrict__ W2, const float* __restrict__ Wa)
{
    const float s0o = (o & 1) ? -1.f : 1.f;
    const float s1o = ((o >> 1) & 1) ? -1.f : 1.f;
    const float s2o = ((o >> 2) & 1) ? -1.f : 1.f;
    const float4 w0 = *(const float4*)(W0 + (o >> 1) * 256 + (i0 >> 1));
    const float2 w1 = *(const float2*)(W1 + (o >> 2) * 128 + (i0 >> 2));
    const float  w2 = W2[(o >> 3) * 64 + (i0 >> 3)];
    const float  wa = Wa[(o >> 3) * 64 + (i0 >> 3)];
    const float base = 0.125f * wa;
    const float c2   = 0.125f * s2o * w2;
    const float c1   = 0.25f  * s1o;
    const float c0   = 0.5f   * s0o;
    const float w0a[4] = { w0.x, w0.y, w0.z, w0.w };
    const float w1a[2] = { w1.x, w1.y };
    float g[8];
    #pragma unroll
    for (int e = 0; e < 8; ++e) {
        const float t2 = ((e >> 2) & 1) ? -c2 : c2;
        const float t1 = (((e >> 1) & 1) ? -c1 : c1) * w1a[e >> 2];
        const float t0 = ((e & 1) ? -c0 : c0) * w0a[e >> 1];
        g[e] = base + t2 + t1 + t0;
    }
    i32x4 p = { (int)pack2(g[0],g[1]), (int)pack2(g[2],g[3]),
                (int)pack2(g[4],g[5]), (int)pack2(g[6],g[7]) };
    return cast8(p);
}

// prep: build G in MFMA-fragment blob order + bias vector g.
// blob = otg*16 + ks (512 blobs); lane holds G[o=otg*16+(lane&15)][k=ks*32+(lane>>4)*8+e].
// 16B/lane, 1KB/blob, 512KB total; bias g (512 f32) after.
__global__ void prep(const float* __restrict__ W0, const float* __restrict__ b0,
                     const float* __restrict__ W1, const float* __restrict__ b1,
                     const float* __restrict__ W2, const float* __restrict__ b2,
                     const float* __restrict__ Wa, const float* __restrict__ ba,
                     unsigned short* __restrict__ ws)
{
    const int gid  = blockIdx.x * 256 + threadIdx.x;   // 32768 threads
    const int blob = gid >> 6, lane = gid & 63;
    const int otg  = blob >> 4, ks = blob & 15;
    const int o  = otg * 16 + (lane & 15);
    const int i0 = ks * 32 + ((lane >> 4) * 8);
    bf16x8 f = g_frag(o, i0, W0, W1, W2, Wa);
    i32x4 p; __builtin_memcpy(&p, &f, 16);
    *(i32x4*)(ws + blob * 512 + lane * 8) = p;
    if (gid < 512) {
        float* gv = (float*)(ws + 262144);
        const int oo = gid;
        const float s0 = (oo & 1) ? -C1f : C1f;
        const float s1 = ((oo >> 1) & 1) ? -C2f : C2f;
        const float s2 = ((oo >> 2) & 1) ? -C3f : C3f;
        gv[oo] = C3f * ba[oo >> 3] + s2 * b2[oo >> 3] + s1 * b1[oo >> 2] + s0 * b0[oo >> 1];
    }
}

// main: out = x @ G^T + g.  Block: 256 rows x 256 cols (col-half), 16 waves.
// Wave owns ONE 16-col tile; its full-K G (16 fragments, 64 VGPR) is loaded ONCE
// and reused for all 256 rows.  x streams through double-buffered LDS in
// 32-row chunks (T14 split: issue loads -> compute -> ds_write -> barrier).
// mfma(G_frag, x_frag, acc): C col(lane&15)=x-row, row((lane>>4)*4+j)=out-col
// -> lane holds 4 consecutive out cols => float4 stores.
template<int USE_WS>
__global__ __launch_bounds__(NT, 4)
void wavelet_gemm(const float* __restrict__ x,
                  const float* __restrict__ W0, const float* __restrict__ b0,
                  const float* __restrict__ W1, const float* __restrict__ b1,
                  const float* __restrict__ W2, const float* __restrict__ b2,
                  const float* __restrict__ Wa, const float* __restrict__ ba,
                  const unsigned short* __restrict__ wsb,
                  float* __restrict__ out)
{
    __shared__ char lds[2 * CH * RB];     // 66560 B

    const int tid  = threadIdx.x;
    const int lane = tid & 63;
    const int wave = tid >> 6;            // 0..15
    const int bid  = blockIdx.x;
    const int chalf = bid & 1;
    const long rowblk = (long)(bid >> 1) * RPB;
    const int otg  = chalf * 16 + wave;   // global col-tile 0..31
    const int col0 = otg * 16;
    const int bc0  = col0 + ((lane >> 4) << 2);   // this lane's 4 out cols

    // ---- B: this wave's full-K G fragments, loaded once (64 VGPR) ----
    bf16x8 B[16];
    if (USE_WS) {
        #pragma unroll
        for (int ks = 0; ks < 16; ++ks)
            B[ks] = cast8(*(const i32x4*)(wsb + ((size_t)(otg * 16 + ks) * 512) + lane * 8));
    } else {
        #pragma unroll
        for (int ks = 0; ks < 16; ++ks)
            B[ks] = g_frag(col0 + (lane & 15), ks * 32 + ((lane >> 4) * 8), W0, W1, W2, Wa);
    }
    // pin B values so the loads cannot be rematerialized inside the chunk loop
    #pragma unroll
    for (int ks = 0; ks < 16; ++ks) {
        i32x4 t; __builtin_memcpy(&t, &B[ks], 16);
        asm volatile("" : "+v"(t));
        __builtin_memcpy(&B[ks], &t, 16);
    }

    // bias for this lane's 4 cols
    f32x4 gv4;
    if (USE_WS) {
        const float4 g4 = *(const float4*)((const float*)(wsb + 262144) + bc0);
        gv4 = f32x4{ g4.x, g4.y, g4.z, g4.w };
    } else {
        #pragma unroll
        for (int j = 0; j < 4; ++j) {
            const int col = bc0 + j;
            const float s0 = (col & 1) ? -C1f : C1f;
            const float s1 = ((col >> 1) & 1) ? -C2f : C2f;
            const float s2 = ((col >> 2) & 1) ? -C3f : C3f;
            gv4[j] = C3f * ba[col >> 3] + s2 * b2[col >> 3] + s1 * b1[col >> 2] + s0 * b0[col >> 1];
        }
    }

    // staging: chunk = 32 rows x 512 f32 = 4096 float4; 4 per thread
    auto ldx = [&](int c, f32x4* v) {
        const f32x4* xb = (const f32x4*)(x + (rowblk + (long)c * CH) * 512);
        #pragma unroll
        for (int i = 0; i < 4; ++i) v[i] = xb[i * NT + tid];
    };
    auto stx = [&](int b, const f32x4* v) {
        char* base = lds + b * (CH * RB);
        #pragma unroll
        for (int i = 0; i < 4; ++i) {
            const int f = i * NT + tid;
            const int row = f >> 7, c4 = f & 127;
            u32x2 p = { pack2(v[i][0], v[i][1]), pack2(v[i][2], v[i][3]) };
            *(u32x2*)(base + row * RB + c4 * 8) = p;
        }
    };
    // compute one 32-row chunk: 2 m-subtiles, 16 ks each
    auto compute = [&](int b, int c) {
        const char* base = lds + b * (CH * RB);
        const char* pa0 = base + (lane & 15) * RB + ((lane >> 4) * 16);
        const char* pa1 = pa0 + 16 * RB;
        f32x4 acc0 = {}, acc1 = {};
        #pragma unroll
        for (int ks = 0; ks < 16; ++ks) {
            bf16x8 a0 = cast8(*(const i32x4*)(pa0 + ks * 64));
            bf16x8 a1 = cast8(*(const i32x4*)(pa1 + ks * 64));
            acc0 = __builtin_amdgcn_mfma_f32_16x16x32_bf16(B[ks], a0, acc0, 0, 0, 0);
            acc1 = __builtin_amdgcn_mfma_f32_16x16x32_bf16(B[ks], a1, acc1, 0, 0, 0);
        }
        const long r0 = rowblk + (long)c * CH + (lane & 15);
        *(f32x4*)(out + r0 * 512 + bc0)        = acc0 + gv4;
        *(f32x4*)(out + (r0 + 16) * 512 + bc0) = acc1 + gv4;
    };

    // ---- prologue + pipelined chunk loop ----
    {
        f32x4 v[4];
        ldx(0, v);
        stx(0, v);
    }
    __syncthreads();
    #pragma unroll 1
    for (int c = 0; c < NCHUNK; ++c) {
        f32x4 vn[4];
        if (c < NCHUNK - 1) ldx(c + 1, vn);   // issue early (T14)
        compute(c & 1, c);
        if (c < NCHUNK - 1) stx((c + 1) & 1, vn);  // vmcnt wait lands here
        __syncthreads();
    }
}

extern "C" void kernel_launch(void* const* d_in, const int* in_sizes, int n_in,
                              void* d_out, int out_size, void* d_ws, size_t ws_size,
                              hipStream_t stream)
{
    const float* x  = (const float*)d_in[0];
    const float* W0 = (const float*)d_in[1];
    const float* b0 = (const float*)d_in[2];
    const float* W1 = (const float*)d_in[3];
    const float* b1 = (const float*)d_in[4];
    const float* W2 = (const float*)d_in[5];
    const float* b2 = (const float*)d_in[6];
    const float* Wa = (const float*)d_in[7];
    const float* ba = (const float*)d_in[8];
    float* out = (float*)d_out;

    const int nrows = in_sizes[0] / 512;      // 65536
    const int nblk  = (nrows / RPB) * 2;      // 512 (row-groups x col-halves)

    if (ws_size >= (size_t)(524288 + 2048)) {
        unsigned short* ws = (unsigned short*)d_ws;
        prep<<<128, 256, 0, stream>>>(W0, b0, W1, b1, W2, b2, Wa, ba, ws);
        wavelet_gemm<1><<<nblk, NT, 0, stream>>>(x, W0, b0, W1, b1, W2, b2, Wa, ba, ws, out);
    } else {
        wavelet_gemm<0><<<nblk, NT, 0, stream>>>(x, W0, b0, W1, b1, W2, b2, Wa, ba, nullptr, out);
    }
}